// Round 1
// baseline (6572.215 us; speedup 1.0000x reference)
//
#include <hip/hip_runtime.h>
#include <math.h>

typedef _Float16 f16x8 __attribute__((ext_vector_type(8)));
typedef float    f32x4 __attribute__((ext_vector_type(4)));

#define NB 16
#define NP 2048
#define NH 2048
#define ND 1024
#define MT 32          // premise rows per block
#define NT 64          // hypothesis cols per iteration
#define SCALE 0.03125f // 1/sqrt(1024)

// Load 8 consecutive fp32 (16B-aligned x2) and convert to 8 f16 (one MFMA frag).
__device__ __forceinline__ f16x8 cvt8(const float* __restrict__ p) {
  f32x4 x = *(const f32x4* __restrict__)p;
  f32x4 y = *(const f32x4* __restrict__)(p + 4);
  f16x8 r;
  r[0] = (_Float16)x[0]; r[1] = (_Float16)x[1];
  r[2] = (_Float16)x[2]; r[3] = (_Float16)x[3];
  r[4] = (_Float16)y[0]; r[5] = (_Float16)y[1];
  r[6] = (_Float16)y[2]; r[7] = (_Float16)y[3];
  return r;
}

// MFMA 16x16x32 f16 layouts (HW-verified per guide m89/m120):
//   A: m = lane&15, k = (lane>>4)*8 + j (j=0..7, contiguous)
//   B: n = lane&15, k = (lane>>4)*8 + j
//   C/D: col = lane&15, row = (lane>>4)*4 + reg
__global__ __launch_bounds__(256, 2)
void uniattn(const float* __restrict__ Q,  const float* __restrict__ PM,
             const float* __restrict__ KV, const float* __restrict__ HM,
             float* __restrict__ OUT)
{
  const int bid  = blockIdx.x;
  const int b    = bid >> 6;           // 64 p-tiles per batch
  const int p0   = (bid & 63) * MT;
  const int tid  = threadIdx.x;
  const int w    = tid >> 6;           // wave 0..3
  const int lane = tid & 63;
  const int qd   = lane >> 4;          // quad 0..3
  const int c16  = lane & 15;
  const int rt   = w & 1;              // S row-tile this wave computes (phase A)
  const int wp   = w >> 1;             // S col-pair group (phase A)

  __shared__ float pm_s[2][2][16];     // per-row partial max  [rt][wp][row]
  __shared__ float pl_s[2][2][16];     // per-row partial sum
  __shared__ float m_s[32];            // running row max
  __shared__ float l_s[32];            // running row denom
  __shared__ float a_s[32];            // per-iter rescale alpha
  __shared__ float rec_s[32];          // final pmask/l
  __shared__ __align__(16) _Float16 Pt[32][72];  // P~ tile, +8 f16 pad (bank fix)

  if (tid < 32) { m_s[tid] = -1e30f; l_s[tid] = 0.0f; }
  __syncthreads();

  // O accumulator: wave w owns d-cols [w*256, w*256+256): 2 row-tiles x 16 col-tiles
  f32x4 Oacc[2][16];
#pragma unroll
  for (int r = 0; r < 2; ++r)
#pragma unroll
    for (int t = 0; t < 16; ++t)
      Oacc[r][t] = (f32x4){0.f, 0.f, 0.f, 0.f};

  const float* Qb = Q  + ((size_t)b * NP + p0) * ND;
  const float* Kb = KV + (size_t)b * NH * ND;
  const float* hm = HM + (size_t)b * NH;
  const float* aRow = Qb + (rt * 16 + c16) * ND + qd * 8;

#pragma unroll 1
  for (int h0 = 0; h0 < NH; h0 += NT) {
    // ---------- Phase A: S = Q K^T (rows rt*16.., cols {2wp,2wp+1}*16..) ----------
    f32x4 S0 = {0.f,0.f,0.f,0.f}, S1 = {0.f,0.f,0.f,0.f};
    const float* bRow0 = Kb + (size_t)(h0 + (wp*2+0)*16 + c16) * ND + qd * 8;
    const float* bRow1 = Kb + (size_t)(h0 + (wp*2+1)*16 + c16) * ND + qd * 8;
#pragma unroll 2
    for (int kc = 0; kc < 32; ++kc) {
      f16x8 af = cvt8(aRow  + kc * 32);
      f16x8 b0 = cvt8(bRow0 + kc * 32);
      f16x8 b1 = cvt8(bRow1 + kc * 32);
      S0 = __builtin_amdgcn_mfma_f32_16x16x32_f16(af, b0, S0, 0, 0, 0);
      S1 = __builtin_amdgcn_mfma_f32_16x16x32_f16(af, b1, S1, 0, 0, 0);
    }

    // ---------- Online softmax over valid cols ----------
    const float km0 = hm[h0 + (wp*2+0)*16 + c16];
    const float km1 = hm[h0 + (wp*2+1)*16 + c16];
    float sm0[4], sm1[4], mx[4];
#pragma unroll
    for (int rg = 0; rg < 4; ++rg) {
      sm0[rg] = (km0 != 0.f) ? S0[rg] * SCALE : -1e30f;
      sm1[rg] = (km1 != 0.f) ? S1[rg] * SCALE : -1e30f;
      mx[rg] = fmaxf(sm0[rg], sm1[rg]);
    }
#pragma unroll
    for (int sh = 1; sh < 16; sh <<= 1)
#pragma unroll
      for (int rg = 0; rg < 4; ++rg)
        mx[rg] = fmaxf(mx[rg], __shfl_xor(mx[rg], sh));
    if (c16 == 0) {
#pragma unroll
      for (int rg = 0; rg < 4; ++rg) pm_s[rt][wp][qd*4+rg] = mx[rg];
    }
    __syncthreads();
    if (wp == 0 && c16 == 0) {           // waves 0/1 own rows 0-15 / 16-31
#pragma unroll
      for (int rg = 0; rg < 4; ++rg) {
        const int rr = qd*4+rg, r = rt*16+rr;
        const float mt = fmaxf(pm_s[rt][0][rr], pm_s[rt][1][rr]);
        const float mo = m_s[r];
        const float mn = fmaxf(mo, mt);
        a_s[r] = __expf(mo - mn);
        m_s[r] = mn;
      }
    }
    __syncthreads();

    float ls[4] = {0.f,0.f,0.f,0.f};
#pragma unroll
    for (int rg = 0; rg < 4; ++rg) {
      const int row = rt*16 + qd*4 + rg;
      const float mn = m_s[row];
      const float pv0 = km0 * __expf(sm0[rg] - mn);
      const float pv1 = km1 * __expf(sm1[rg] - mn);
      Pt[row][(wp*2+0)*16 + c16] = (_Float16)pv0;
      Pt[row][(wp*2+1)*16 + c16] = (_Float16)pv1;
      ls[rg] = pv0 + pv1;
    }
#pragma unroll
    for (int sh = 1; sh < 16; sh <<= 1)
#pragma unroll
      for (int rg = 0; rg < 4; ++rg)
        ls[rg] += __shfl_xor(ls[rg], sh);
    if (c16 == 0) {
#pragma unroll
      for (int rg = 0; rg < 4; ++rg) pl_s[rt][wp][qd*4+rg] = ls[rg];
    }
    __syncthreads();                     // Pt + pl complete
    if (wp == 0 && c16 == 0) {
#pragma unroll
      for (int rg = 0; rg < 4; ++rg) {
        const int rr = qd*4+rg, r = rt*16+rr;
        l_s[r] = l_s[r] * a_s[r] + pl_s[rt][0][rr] + pl_s[rt][1][rr];
      }
    }

    // ---------- Phase C: O = O*alpha + P~ V ; wave owns d-slice [w*256,+256) ----------
#pragma unroll
    for (int r2 = 0; r2 < 2; ++r2) {
      float av[4];
#pragma unroll
      for (int rg = 0; rg < 4; ++rg) av[rg] = a_s[r2*16 + qd*4 + rg];
#pragma unroll
      for (int t = 0; t < 16; ++t)
#pragma unroll
        for (int rg = 0; rg < 4; ++rg) Oacc[r2][t][rg] *= av[rg];
    }
    const int dbase = w * 256;
#pragma unroll
    for (int kc2 = 0; kc2 < 2; ++kc2) {
      f16x8 pa0 = *(const f16x8*)&Pt[c16][kc2*32 + qd*8];
      f16x8 pa1 = *(const f16x8*)&Pt[16 + c16][kc2*32 + qd*8];
      const float* vcol = Kb + (size_t)(h0 + kc2*32 + qd*8) * ND + dbase + c16;
#pragma unroll 2
      for (int t = 0; t < 16; ++t) {
        f16x8 vb;
#pragma unroll
        for (int j = 0; j < 8; ++j)
          vb[j] = (_Float16)vcol[(size_t)j * ND + t*16];
        Oacc[0][t] = __builtin_amdgcn_mfma_f32_16x16x32_f16(pa0, vb, Oacc[0][t], 0, 0, 0);
        Oacc[1][t] = __builtin_amdgcn_mfma_f32_16x16x32_f16(pa1, vb, Oacc[1][t], 0, 0, 0);
      }
    }
    __syncthreads();                     // protect Pt/a_s before next iteration
  }

  // ---------- Epilogue: out = O / l * premise_mask ----------
  if (tid < 32) rec_s[tid] = PM[(size_t)b * NP + p0 + tid] / (l_s[tid] + 1e-13f);
  __syncthreads();
#pragma unroll
  for (int r2 = 0; r2 < 2; ++r2) {
    float rv[4];
#pragma unroll
    for (int rg = 0; rg < 4; ++rg) rv[rg] = rec_s[r2*16 + qd*4 + rg];
#pragma unroll
    for (int t = 0; t < 16; ++t) {
      float* op = OUT + ((size_t)b * NP + p0 + r2*16 + qd*4) * ND + w*256 + t*16 + c16;
#pragma unroll
      for (int rg = 0; rg < 4; ++rg)
        op[(size_t)rg * ND] = Oacc[r2][t][rg] * rv[rg];
    }
  }
}

extern "C" void kernel_launch(void* const* d_in, const int* in_sizes, int n_in,
                              void* d_out, int out_size, void* d_ws, size_t ws_size,
                              hipStream_t stream) {
  const float* Q  = (const float*)d_in[0];  // premise_batch   [16][2048][1024]
  const float* PM = (const float*)d_in[1];  // premise_mask    [16][2048]
  const float* KV = (const float*)d_in[2];  // hypothesis_batch[16][2048][1024]
  const float* HM = (const float*)d_in[3];  // hypothesis_mask [16][2048]
  float* OUT = (float*)d_out;               // [16][2048][1024] fp32

  dim3 grid(NB * (NP / MT));   // 1024 blocks
  dim3 block(256);
  hipLaunchKernelGGL(uniattn, grid, block, 0, stream, Q, PM, KV, HM, OUT);
}

// Round 2
// 3348.917 us; speedup vs baseline: 1.9625x; 1.9625x over previous
//
#include <hip/hip_runtime.h>
#include <math.h>

typedef _Float16 f16x8 __attribute__((ext_vector_type(8)));
typedef float    f32x4 __attribute__((ext_vector_type(4)));

#define NB 16
#define NP 2048
#define NH 2048
#define ND 1024
#define MT 32          // premise rows per block
#define NT 64          // hypothesis cols per iteration
#define SCALE 0.03125f // 1/sqrt(1024)

// Load 8 consecutive fp32 (16B-aligned x2) and convert to 8 f16 (one MFMA frag).
__device__ __forceinline__ f16x8 cvt8(const float* __restrict__ p) {
  f32x4 x = *(const f32x4* __restrict__)p;
  f32x4 y = *(const f32x4* __restrict__)(p + 4);
  f16x8 r;
  r[0] = (_Float16)x[0]; r[1] = (_Float16)x[1];
  r[2] = (_Float16)x[2]; r[3] = (_Float16)x[3];
  r[4] = (_Float16)y[0]; r[5] = (_Float16)y[1];
  r[6] = (_Float16)y[2]; r[7] = (_Float16)y[3];
  return r;
}

// MFMA 16x16x32 f16 layouts (HW-verified per guide m89/m120):
//   A: m = lane&15, k = (lane>>4)*8 + j (j=0..7, contiguous)
//   B: n = lane&15, k = (lane>>4)*8 + j
//   C/D: col = lane&15, row = (lane>>4)*4 + reg
__global__ __launch_bounds__(256, 2)
void uniattn(const float* __restrict__ Q,  const float* __restrict__ PM,
             const float* __restrict__ KV, const float* __restrict__ HM,
             float* __restrict__ OUT)
{
  const int bid  = blockIdx.x;
  const int b    = bid >> 6;           // 64 p-tiles per batch
  const int p0   = (bid & 63) * MT;
  const int tid  = threadIdx.x;
  const int w    = tid >> 6;           // wave 0..3
  const int lane = tid & 63;
  const int qd   = lane >> 4;          // quad 0..3
  const int c16  = lane & 15;
  const int rt   = w & 1;              // S row-tile this wave computes (phase A)
  const int wp   = w >> 1;             // S col-pair group (phase A)

  __shared__ float pm_s[2][2][16];     // per-row partial max  [rt][wp][row]
  __shared__ float pl_s[2][2][16];     // per-row partial sum
  __shared__ float m_s[32];            // running row max
  __shared__ float l_s[32];            // running row denom
  __shared__ float a_s[32];            // per-iter rescale alpha
  __shared__ float rec_s[32];          // final pmask/l
  __shared__ __align__(16) _Float16 Pt[32][72];  // P~ tile, +8 f16 pad (bank fix)

  if (tid < 32) { m_s[tid] = -1e30f; l_s[tid] = 0.0f; }
  __syncthreads();

  // O accumulator: wave w owns d-cols [w*256, w*256+256): 2 row-tiles x 16 col-tiles
  f32x4 Oacc[2][16];
#pragma unroll
  for (int r = 0; r < 2; ++r)
#pragma unroll
    for (int t = 0; t < 16; ++t)
      Oacc[r][t] = (f32x4){0.f, 0.f, 0.f, 0.f};

  const float* Qb = Q  + ((size_t)b * NP + p0) * ND;
  const float* Kb = KV + (size_t)b * NH * ND;
  const float* hm = HM + (size_t)b * NH;
  const float* aRow = Qb + (rt * 16 + c16) * ND + qd * 8;

#pragma unroll 1
  for (int h0 = 0; h0 < NH; h0 += NT) {
    // ---------- Phase A: S = Q K^T (rows rt*16.., cols {2wp,2wp+1}*16..) ----------
    f32x4 S0 = {0.f,0.f,0.f,0.f}, S1 = {0.f,0.f,0.f,0.f};
    const float* bRow0 = Kb + (size_t)(h0 + (wp*2+0)*16 + c16) * ND + qd * 8;
    const float* bRow1 = Kb + (size_t)(h0 + (wp*2+1)*16 + c16) * ND + qd * 8;
#pragma unroll 2
    for (int kc = 0; kc < 32; ++kc) {
      f16x8 af = cvt8(aRow  + kc * 32);
      f16x8 b0 = cvt8(bRow0 + kc * 32);
      f16x8 b1 = cvt8(bRow1 + kc * 32);
      S0 = __builtin_amdgcn_mfma_f32_16x16x32_f16(af, b0, S0, 0, 0, 0);
      S1 = __builtin_amdgcn_mfma_f32_16x16x32_f16(af, b1, S1, 0, 0, 0);
    }

    // ---------- Online softmax over valid cols ----------
    const float km0 = hm[h0 + (wp*2+0)*16 + c16];
    const float km1 = hm[h0 + (wp*2+1)*16 + c16];
    float sm0[4], sm1[4], mx[4];
#pragma unroll
    for (int rg = 0; rg < 4; ++rg) {
      sm0[rg] = (km0 != 0.f) ? S0[rg] * SCALE : -1e30f;
      sm1[rg] = (km1 != 0.f) ? S1[rg] * SCALE : -1e30f;
      mx[rg] = fmaxf(sm0[rg], sm1[rg]);
    }
#pragma unroll
    for (int sh = 1; sh < 16; sh <<= 1)
#pragma unroll
      for (int rg = 0; rg < 4; ++rg)
        mx[rg] = fmaxf(mx[rg], __shfl_xor(mx[rg], sh));
    if (c16 == 0) {
#pragma unroll
      for (int rg = 0; rg < 4; ++rg) pm_s[rt][wp][qd*4+rg] = mx[rg];
    }
    __syncthreads();
    if (wp == 0 && c16 == 0) {           // waves 0/1 own rows 0-15 / 16-31
#pragma unroll
      for (int rg = 0; rg < 4; ++rg) {
        const int rr = qd*4+rg, r = rt*16+rr;
        const float mt = fmaxf(pm_s[rt][0][rr], pm_s[rt][1][rr]);
        const float mo = m_s[r];
        const float mn = fmaxf(mo, mt);
        a_s[r] = __expf(mo - mn);
        m_s[r] = mn;
      }
    }
    __syncthreads();

    float ls[4] = {0.f,0.f,0.f,0.f};
#pragma unroll
    for (int rg = 0; rg < 4; ++rg) {
      const int row = rt*16 + qd*4 + rg;
      const float mn = m_s[row];
      const float pv0 = km0 * __expf(sm0[rg] - mn);
      const float pv1 = km1 * __expf(sm1[rg] - mn);
      Pt[row][(wp*2+0)*16 + c16] = (_Float16)pv0;
      Pt[row][(wp*2+1)*16 + c16] = (_Float16)pv1;
      ls[rg] = pv0 + pv1;
    }
#pragma unroll
    for (int sh = 1; sh < 16; sh <<= 1)
#pragma unroll
      for (int rg = 0; rg < 4; ++rg)
        ls[rg] += __shfl_xor(ls[rg], sh);
    if (c16 == 0) {
#pragma unroll
      for (int rg = 0; rg < 4; ++rg) pl_s[rt][wp][qd*4+rg] = ls[rg];
    }
    __syncthreads();                     // Pt + pl complete
    if (wp == 0 && c16 == 0) {
#pragma unroll
      for (int rg = 0; rg < 4; ++rg) {
        const int rr = qd*4+rg, r = rt*16+rr;
        l_s[r] = l_s[r] * a_s[r] + pl_s[rt][0][rr] + pl_s[rt][1][rr];
      }
    }

    // ---------- Phase C: O = O*alpha + P~ V ; wave owns d-slice [w*256,+256) ----------
#pragma unroll
    for (int r2 = 0; r2 < 2; ++r2) {
      float av[4];
#pragma unroll
      for (int rg = 0; rg < 4; ++rg) av[rg] = a_s[r2*16 + qd*4 + rg];
#pragma unroll
      for (int t = 0; t < 16; ++t)
#pragma unroll
        for (int rg = 0; rg < 4; ++rg) Oacc[r2][t][rg] *= av[rg];
    }
    const int dbase = w * 256;
#pragma unroll
    for (int kc2 = 0; kc2 < 2; ++kc2) {
      f16x8 pa0 = *(const f16x8*)&Pt[c16][kc2*32 + qd*8];
      f16x8 pa1 = *(const f16x8*)&Pt[16 + c16][kc2*32 + qd*8];
      const float* vcol = Kb + (size_t)(h0 + kc2*32 + qd*8) * ND + dbase + c16;
#pragma unroll
      for (int t = 0; t < 16; ++t) {   // FULL unroll: t must be compile-time so
        f16x8 vb;                      // Oacc[][t] stays in registers (R1: unroll 2
#pragma unroll                         // forced Oacc to scratch -> 12.7GB writes)
        for (int j = 0; j < 8; ++j)
          vb[j] = (_Float16)vcol[(size_t)j * ND + t*16];
        Oacc[0][t] = __builtin_amdgcn_mfma_f32_16x16x32_f16(pa0, vb, Oacc[0][t], 0, 0, 0);
        Oacc[1][t] = __builtin_amdgcn_mfma_f32_16x16x32_f16(pa1, vb, Oacc[1][t], 0, 0, 0);
      }
    }
    __syncthreads();                     // protect Pt/a_s before next iteration
  }

  // ---------- Epilogue: out = O / l * premise_mask ----------
  if (tid < 32) rec_s[tid] = PM[(size_t)b * NP + p0 + tid] / (l_s[tid] + 1e-13f);
  __syncthreads();
#pragma unroll
  for (int r2 = 0; r2 < 2; ++r2) {
    float rv[4];
#pragma unroll
    for (int rg = 0; rg < 4; ++rg) rv[rg] = rec_s[r2*16 + qd*4 + rg];
#pragma unroll
    for (int t = 0; t < 16; ++t) {
      float* op = OUT + ((size_t)b * NP + p0 + r2*16 + qd*4) * ND + w*256 + t*16 + c16;
#pragma unroll
      for (int rg = 0; rg < 4; ++rg)
        op[(size_t)rg * ND] = Oacc[r2][t][rg] * rv[rg];
    }
  }
}

extern "C" void kernel_launch(void* const* d_in, const int* in_sizes, int n_in,
                              void* d_out, int out_size, void* d_ws, size_t ws_size,
                              hipStream_t stream) {
  const float* Q  = (const float*)d_in[0];  // premise_batch   [16][2048][1024]
  const float* PM = (const float*)d_in[1];  // premise_mask    [16][2048]
  const float* KV = (const float*)d_in[2];  // hypothesis_batch[16][2048][1024]
  const float* HM = (const float*)d_in[3];  // hypothesis_mask [16][2048]
  float* OUT = (float*)d_out;               // [16][2048][1024] fp32

  dim3 grid(NB * (NP / MT));   // 1024 blocks
  dim3 block(256);
  hipLaunchKernelGGL(uniattn, grid, block, 0, stream, Q, PM, KV, HM, OUT);
}